// Round 6
// baseline (328.923 us; speedup 1.0000x reference)
//
#include <hip/hip_runtime.h>
#include <hip/hip_bf16.h>

// I/O is FLOAT32 (reference dtype). bf16 only internal (MFMA operands).
typedef __bf16 bf16_t;
typedef bf16_t bf16x8 __attribute__((ext_vector_type(8)));
typedef bf16_t bf16x4 __attribute__((ext_vector_type(4)));
typedef float  f32x4  __attribute__((ext_vector_type(4)));
typedef int    i32x2  __attribute__((ext_vector_type(2)));
typedef int    i32x4  __attribute__((ext_vector_type(4)));

#define MFMA(a,b,c) __builtin_amdgcn_mfma_f32_16x16x32_bf16((a),(b),(c),0,0,0)

// device-scope spin barrier (20 co-resident blocks; ctr zeroed by memsetAsync each launch)
__device__ __forceinline__ void gbar(int* ctr, int phase, int nblk) {
  __syncthreads();
  if (threadIdx.x == 0) {
    __hip_atomic_fetch_add(&ctr[phase], 1, __ATOMIC_RELEASE, __HIP_MEMORY_SCOPE_AGENT);
    while (__hip_atomic_load(&ctr[phase], __ATOMIC_ACQUIRE, __HIP_MEMORY_SCOPE_AGENT) < nblk)
      __builtin_amdgcn_s_sleep(2);
  }
  __syncthreads();
}

// ---------------- M = final_w[:, :256] @ gw_w (bf16) ----------------
__global__ __launch_bounds__(256) void k_M(const float* final_w, const float* gw_w, bf16_t* M16) {
  int o = blockIdx.x, c = threadIdx.x;
  __shared__ float fw[256];
  fw[c] = final_w[o*512 + c];
  __syncthreads();
  float acc = 0.f;
  for (int k = 0; k < 256; ++k) acc += fw[k] * gw_w[k*256 + c];
  M16[o*256 + c] = (bf16_t)acc;
}

// ---------------- x transpose: xTg[b][c][q] = x_flat[b][q*256+c] (bf16) ----------------
__global__ __launch_bounds__(256) void k_trans(const float* x, bf16_t* xTg) {
  int b = blockIdx.y;
  int q = blockIdx.x*64 + (threadIdx.x & 63);
  int w = threadIdx.x >> 6;
  const float* xr = x + b*262144 + q*256;
  bf16_t* o = xTg + b*262144 + q;
  for (int c0 = w*64; c0 < w*64 + 64; c0 += 4) {
    f32x4 v = *(const f32x4*)(xr + c0);
    o[(c0+0)*1024] = (bf16_t)v[0];
    o[(c0+1)*1024] = (bf16_t)v[1];
    o[(c0+2)*1024] = (bf16_t)v[2];
    o[(c0+3)*1024] = (bf16_t)v[3];
  }
}

// ---------------- fused small graph chain: grid 20, block 320 ----------------
__global__ __launch_bounds__(320) void k_graph(const float* emb, const float* adj,
    const float* wq, const float* bq, const float* wk, const float* bk,
    const float* wv, const float* bv, const float* wo, const float* bo,
    const float* gc1_w, const float* gc2_w, const float* final_w,
    int* bar, float* qkv, float* n1, float* n2, float* h1, float* h2,
    float* rg, float* u) {
  int j = blockIdx.x, t = threadIdx.x;
  __shared__ float er[304], n2s[304], ks[6000], qrow[304];
  __shared__ float att_s[20], drt_l[20], adjr[20], g1s[256];
  if (t < 300) er[t] = emb[j*300 + t];
  __syncthreads();
  if (t < 300) {
    float aq = bq[t], ak = bk[t], av = bv[t];
    for (int d = 0; d < 300; ++d) {
      float e = er[d];
      aq += e * wq[d*300 + t];
      ak += e * wk[d*300 + t];
      av += e * wv[d*300 + t];
    }
    qkv[j*300 + t] = aq;
    qkv[6000 + j*300 + t] = ak;
    qkv[12000 + j*300 + t] = av;
  }
  gbar(bar, 0, 20);
  for (int i = t; i < 6000; i += 320) ks[i] = qkv[6000 + i];
  if (t < 300) qrow[t] = qkv[j*300 + t];
  if (t >= 300 && t < 320) {
    int i = t - 300; float s = 1.f;
    for (int jj = 0; jj < 20; ++jj) s += adj[i*20 + jj];
    drt_l[i] = rsqrtf(s);
  }
  __syncthreads();
  if (t < 20) {
    float acc = 0.f;
    for (int d = 0; d < 300; ++d) acc += qrow[d] * ks[t*300 + d];
    att_s[t] = acc * 0.05773502691896258f;
  }
  __syncthreads();
  if (t == 0) {
    float m = -1e30f;
    for (int jj = 0; jj < 20; ++jj) m = fmaxf(m, att_s[jj]);
    float s = 0.f;
    for (int jj = 0; jj < 20; ++jj) { float e = __expf(att_s[jj] - m); att_s[jj] = e; s += e; }
    float inv = 0.05f / s;              // includes mean over i (1/20)
    for (int jj = 0; jj < 20; ++jj) att_s[jj] *= inv;
  }
  __syncthreads();
  if (t < 300) {
    const float* v = qkv + 12000;
    float acc = 0.f;
    for (int jj = 0; jj < 20; ++jj) acc += att_s[jj] * v[jj*300 + t];
    atomicAdd(&n1[t], acc);
  }
  if (t < 20) {
    float a = adj[j*20 + t] + (t == j ? 1.f : 0.f);
    adjr[t] = drt_l[j] * a * drt_l[t];
  }
  gbar(bar, 1, 20);
  if (t < 15) {
    int tt = j*15 + t;
    float acc = bo[tt];
    for (int d = 0; d < 300; ++d) acc += n1[d] * wo[d*300 + tt];
    n2[tt] = acc;
  }
  gbar(bar, 2, 20);
  for (int i = t; i < 300; i += 320) n2s[i] = n2[i];
  __syncthreads();
  if (t < 256) {
    float acc = 0.f;
    for (int d = 0; d < 300; ++d) acc += (er[d] + n2s[d]) * gc1_w[d*256 + t];
    h1[j*256 + t] = acc;
  }
  gbar(bar, 3, 20);
  if (t < 256) {
    float acc = 0.f;
    for (int m = 0; m < 20; ++m) acc += adjr[m] * h1[m*256 + t];
    g1s[t] = fmaxf(acc, 0.f);
  }
  __syncthreads();
  if (t < 256) {
    float acc = 0.f;
    for (int d = 0; d < 256; ++d) acc += g1s[d] * gc2_w[d*256 + t];
    h2[j*256 + t] = acc;
  }
  gbar(bar, 4, 20);
  if (t < 256) {
    float acc = 0.f;
    for (int m = 0; m < 20; ++m) acc += adjr[m] * h2[m*256 + t];
    atomicAdd(&rg[t], fmaxf(acc, 0.f));
  }
  gbar(bar, 5, 20);
  if (j == 0 && t < 256) {
    float acc = 0.f;
    for (int k = 0; k < 256; ++k) acc += final_w[t*512 + 256 + k] * rg[k];
    u[t] = acc;
  }
}

// ---------------- big path ----------------

// phi -> fBT[b][q][32] (q-major, m>=16 zero) AND fBn[b][m][q] (natural flat = phi layout),
// fmax, csum + cmax, s_raw, xsum partials.  grid (9, 16): role 0..7 -> 128 hw; role 8 -> xsum.
__global__ __launch_bounds__(256) void k_phis(const float* x, const float* phi_w,
    const float* phi_b, const float* s2l_w,
    bf16_t* fBT, bf16_t* fBn, float* fmaxb, float* s_raw, float* xsum,
    float* csum, float* cmaxb) {
  int b = blockIdx.y, role = blockIdx.x, t = threadIdx.x;
  const float* xb = x + b*262144;
  if (role == 8) {
    int wv = t >> 6, lane = t & 63;
    for (int c = wv; c < 256; c += 4) {
      float acc = 0.f;
      const float* p = xb + c*1024 + lane;
      #pragma unroll
      for (int k = 0; k < 16; ++k) acc += p[k*64];
      #pragma unroll
      for (int off = 32; off; off >>= 1) acc += __shfl_down(acc, off, 64);
      if (lane == 0) atomicAdd(&xsum[b*256 + c], acc);
    }
    return;
  }
  __shared__ float pw[4096], wi[256], pb[16];
  __shared__ float phs[128][18];
  __shared__ unsigned fmu[16];
  __shared__ unsigned cmu;
  for (int i = t; i < 4096; i += 256) pw[i] = phi_w[i];
  wi[t] = s2l_w[t];
  if (t < 16) { pb[t] = phi_b[t]; fmu[t] = 0u; }
  if (t == 0) cmu = 0u;
  __syncthreads();
  int hwl = t & 127, half = t >> 7;
  int hw = role*128 + hwl;
  float ph[16];
  #pragma unroll
  for (int o = 0; o < 16; ++o) ph[o] = 0.f;
  float sacc = 0.f;
  for (int ci = 0; ci < 128; ++ci) {
    int c = half*128 + ci;
    float xv = xb[c*1024 + hw];
    sacc += wi[c] * xv;
    #pragma unroll
    for (int o = 0; o < 16; ++o) ph[o] += pw[o*256 + c] * xv;
  }
  if (half == 0) {
    #pragma unroll
    for (int o = 0; o < 16; ++o) phs[hwl][o] = ph[o];
    phs[hwl][16] = sacc;
  }
  __syncthreads();
  if (half == 1) {
    #pragma unroll
    for (int o = 0; o < 16; ++o) phs[hwl][o] += ph[o];
    s_raw[b*1024 + hw] = phs[hwl][16] + sacc;
  }
  __syncthreads();
  if (half == 0) {   // threads 0..127: finalize row hw (all 16 m)
    float cs = 0.f;
    bf16x8 v0, v1, vz;
    #pragma unroll
    for (int o = 0; o < 16; ++o) {
      float val = fmaxf(phs[hwl][o] + pb[o], 0.f);
      bf16_t bv = (bf16_t)val;
      float vf = (float)bv;
      atomicMax(&fmu[o], __float_as_uint(vf));
      cs += vf;
      if (o < 8) v0[o] = bv; else v1[o-8] = bv;
      fBn[b*16384 + o*1024 + hw] = bv;     // natural (phi-flat) layout
    }
    #pragma unroll
    for (int o = 0; o < 8; ++o) vz[o] = (bf16_t)0.f;
    bf16_t* row = fBT + (b*1024 + hw)*32;
    *(bf16x8*)(row)      = v0;
    *(bf16x8*)(row + 8)  = v1;
    *(bf16x8*)(row + 16) = vz;
    *(bf16x8*)(row + 24) = vz;
    csum[b*1024 + hw] = cs;
    atomicMax(&cmu, __float_as_uint(cs));  // cs >= 0
  }
  __syncthreads();
  if (t < 16) atomicMax((unsigned*)&fmaxb[b*16 + t], fmu[t]);
  if (t == 0) atomicMax((unsigned*)&cmaxb[b], cmu);
}

// dgd = sigmoid(g)-0.5; mcol = softmax_p(s_raw).  grid 16
__global__ __launch_bounds__(256) void k_dgm(const float* xsum, const float* glob_w,
    const float* s_raw, float* dgd, float* mcol) {
  int b = blockIdx.x, t = threadIdx.x;
  __shared__ float xm[256], red[8];
  xm[t] = xsum[b*256 + t] * (1.f / 1024.f);
  __syncthreads();
  if (t < 16) {
    float g = 0.f;
    for (int c = 0; c < 256; ++c) g += glob_w[t*256 + c] * xm[c];
    dgd[b*16 + t] = 0.5f * tanhf(0.5f * g);
  }
  float v[4]; float m = -1e30f;
  #pragma unroll
  for (int i = 0; i < 4; ++i) { v[i] = s_raw[b*1024 + t + i*256]; m = fmaxf(m, v[i]); }
  #pragma unroll
  for (int off = 32; off; off >>= 1) m = fmaxf(m, __shfl_xor(m, off, 64));
  if ((t & 63) == 0) red[t >> 6] = m;
  __syncthreads();
  float bm = fmaxf(fmaxf(red[0], red[1]), fmaxf(red[2], red[3]));
  float e[4]; float sum = 0.f;
  #pragma unroll
  for (int i = 0; i < 4; ++i) { e[i] = __expf(v[i] - bm); sum += e[i]; }
  #pragma unroll
  for (int off = 32; off; off >>= 1) sum += __shfl_xor(sum, off, 64);
  if ((t & 63) == 0) red[4 + (t >> 6)] = sum;
  __syncthreads();
  float inv = 1.f / (red[4] + red[5] + red[6] + red[7]);
  #pragma unroll
  for (int i = 0; i < 4; ++i) mcol[b*1024 + t + i*256] = e[i] * inv;
}

// Fused main. grid 256 (XCD-swizzled), block 512 (8 waves: psub = w&3, chalf = w>>2).
// Barrier-free st-loop: scores via MFMA (A=fBT global, B=e'), E transposed in-wave via
// ds_bpermute, S2u += E @ xTg (global B). Then T in LDS, GEMM2, epilogue.
__global__ __launch_bounds__(512) void k_main(const float* x, const bf16_t* fBT,
    const bf16_t* fBn, const bf16_t* xTg, const bf16_t* M16, const float* fmaxb,
    const float* mcol, const float* u, const float* dgd, const float* csum,
    const float* cmaxb, float* out) {
  int id = blockIdx.x;
  int b = 2*(id & 7) + (id >> 7);        // same-b blocks -> same XCD
  int p0 = ((id >> 3) & 15) * 64;
  int t = threadIdx.x, w = t >> 6, l = t & 63, lr = l & 15, quad = l >> 4;
  int psub = w & 3, chalf = w >> 2;
  __shared__ bf16_t e_s[64*40];          // e' (m>=16 zero)
  __shared__ bf16_t T_ls[64*264];
  __shared__ float fmax_s[16], dgd_s[16], u_s[256], c_s[1024];
  __shared__ float Mb_s[64], ha_s[64], rsinv_s[64];
  const float*  xb   = x   + b*262144;
  const bf16_t* fBTb = fBT + b*32768;
  const bf16_t* fBnb = fBn + b*16384;
  const bf16_t* xTb  = xTg + b*262144;
  for (int i = t; i < 2560; i += 512) e_s[i] = (bf16_t)0.f;
  if (t < 256) u_s[t] = u[t];
  for (int i = t; i < 1024; i += 512) c_s[i] = csum[b*1024 + i];
  if (t < 16) { fmax_s[t] = fmaxb[b*16 + t]; dgd_s[t] = dgd[b*16 + t]; }
  __syncthreads();
  for (int i = t; i < 1024; i += 512) {  // e'[p,m] = x_phi[p][m]*dgd[m]; x_phi = phi-flat view
    int p = i >> 4, m = i & 15;
    e_s[p*40 + m] = (bf16_t)((float)fBnb[p0*16 + i] * dgd_s[m]);
  }
  __syncthreads();
  if (t < 64) {
    float a = 0.f;
    #pragma unroll
    for (int m = 0; m < 16; ++m) a += (float)fBnb[(p0 + t)*16 + m];
    float ha = 0.5f * a;
    ha_s[t] = ha;
    float mb = ha * cmaxb[b];
    #pragma unroll
    for (int m = 0; m < 16; ++m) mb += fmaxf((float)e_s[t*40 + m], 0.f) * fmax_s[m];
    Mb_s[t] = mb;                        // exact upper bound on row max of S
  }
  __syncthreads();
  bf16x8 be = *(const bf16x8*)(e_s + (psub*16 + lr)*40 + quad*8);
  float mb_lane = Mb_s[psub*16 + lr];
  float ha_lane = ha_s[psub*16 + lr];
  int srcA = ((quad & 1)*32 + lr) * 4;   // bpermute byte addr
  int srcB = srcA + 64;
  int sel  = quad >> 1;
  float rs = 0.f;
  f32x4 acc[8];                          // S2u[p=psub*16+quad*4+r][c=chalf*128+cf*16+lr]
  #pragma unroll
  for (int i = 0; i < 8; ++i) acc[i] = (f32x4){0.f, 0.f, 0.f, 0.f};
  for (int st = 0; st < 32; ++st) {
    const bf16_t* fr = fBTb + st*32*32;
    bf16x8 a0 = *(const bf16x8*)(fr + lr*32 + quad*8);
    bf16x8 a1 = *(const bf16x8*)(fr + (16 + lr)*32 + quad*8);
    f32x4 z = {0.f, 0.f, 0.f, 0.f};
    f32x4 s0 = MFMA(a0, be, z);          // s0[r] = S[p=psub*16+lr][q=st*32+quad*4+r]
    f32x4 s1 = MFMA(a1, be, z);          // s1: q = st*32+16+quad*4+r
    bf16x4 e0, e1;
    #pragma unroll
    for (int r = 0; r < 4; ++r) {
      float S0 = s0[r] + ha_lane * c_s[st*32 + quad*4 + r];
      float S1 = s1[r] + ha_lane * c_s[st*32 + 16 + quad*4 + r];
      float E0 = __expf(S0 - mb_lane);
      float E1 = __expf(S1 - mb_lane);
      rs += E0 + E1;
      e0[r] = (bf16_t)E0; e1[r] = (bf16_t)E1;
    }
    // in-wave D-layout -> A-layout transpose of E via bpermute
    i32x2 pe0 = __builtin_bit_cast(i32x2, e0);
    i32x2 pe1 = __builtin_bit_cast(i32x2, e1);
    int t00 = __builtin_amdgcn_ds_bpermute(srcA, pe0[0]);
    int t01 = __builtin_amdgcn_ds_bpermute(srcA, pe0[1]);
    int t02 = __builtin_amdgcn_ds_bpermute(srcB, pe0[0]);
    int t03 = __builtin_amdgcn_ds_bpermute(srcB, pe0[1]);
    int t10 = __builtin_amdgcn_ds_bpermute(srcA, pe1[0]);
    int t11 = __builtin_amdgcn_ds_bpermute(srcA, pe1[1]);
    int t12 = __builtin_amdgcn_ds_bpermute(srcB, pe1[0]);
    int t13 = __builtin_amdgcn_ds_bpermute(srcB, pe1[1]);
    i32x4 av = { sel ? t10 : t00, sel ? t11 : t01, sel ? t12 : t02, sel ? t13 : t03 };
    bf16x8 af = __builtin_bit_cast(bf16x8, av);   // af[j] = E[p=psub*16+lr][q=quad*8+j]
    #pragma unroll
    for (int cf = 0; cf < 8; ++cf) {
      bf16x8 bv = *(const bf16x8*)(xTb + (chalf*128 + cf*16 + lr)*1024 + st*32 + quad*8);
      acc[cf] = MFMA(af, bv, acc[cf]);
    }
  }
  rs += __shfl_xor(rs, 16, 64);
  rs += __shfl_xor(rs, 32, 64);          // full rowsum for p = psub*16+lr
  float inv_l = 1.f / fmaxf(rs, 1e-30f);
  if (w < 4 && l < 16) rsinv_s[psub*16 + lr] = inv_l;
  __syncthreads();
  #pragma unroll
  for (int cf = 0; cf < 8; ++cf)
    #pragma unroll
    for (int r = 0; r < 4; ++r) {
      int p = psub*16 + quad*4 + r;
      int c = chalf*128 + cf*16 + lr;
      float tv = xb[(p0 + p)*256 + c] - acc[cf][r] * rsinv_s[p];
      T_ls[p*264 + c] = (bf16_t)tv;      // spiral[p][c]
    }
  __syncthreads();
  f32x4 acc2[2][4];                      // D2[o=w*32+of*16+quad*4+r][p=pf*16+lr]
  #pragma unroll
  for (int i = 0; i < 2; ++i)
    #pragma unroll
    for (int j = 0; j < 4; ++j) acc2[i][j] = (f32x4){0.f, 0.f, 0.f, 0.f};
  for (int c0 = 0; c0 < 256; c0 += 32) {
    bf16x8 am[2], bt[4];
    #pragma unroll
    for (int of = 0; of < 2; ++of)
      am[of] = *(const bf16x8*)(M16 + (w*32 + of*16 + lr)*256 + c0 + quad*8);
    #pragma unroll
    for (int pf = 0; pf < 4; ++pf)
      bt[pf] = *(const bf16x8*)(T_ls + (pf*16 + lr)*264 + c0 + quad*8);
    #pragma unroll
    for (int of = 0; of < 2; ++of)
      #pragma unroll
      for (int pf = 0; pf < 4; ++pf) acc2[of][pf] = MFMA(am[of], bt[pf], acc2[of][pf]);
  }
  float* outb = out + b*262144;
  #pragma unroll
  for (int of = 0; of < 2; ++of)
    #pragma unroll
    for (int pf = 0; pf < 4; ++pf)
      #pragma unroll
      for (int r = 0; r < 4; ++r) {
        int o = w*32 + of*16 + quad*4 + r;
        int pg = p0 + pf*16 + lr;
        float v = acc2[of][pf][r] + mcol[b*1024 + pg] * u_s[o] + xb[o*1024 + pg];
        outb[o*1024 + pg] = fmaxf(v, 0.f);
      }
}

// ---------------- launch ----------------

extern "C" void kernel_launch(void* const* d_in, const int* in_sizes, int n_in,
                              void* d_out, int out_size, void* d_ws, size_t ws_size,
                              hipStream_t stream) {
  (void)in_sizes; (void)n_in; (void)out_size; (void)ws_size;
  const float* x       = (const float*)d_in[0];
  const float* emb     = (const float*)d_in[1];
  const float* adj     = (const float*)d_in[2];
  const float* wq      = (const float*)d_in[3];
  const float* bq      = (const float*)d_in[4];
  const float* wk      = (const float*)d_in[5];
  const float* bk      = (const float*)d_in[6];
  const float* wv      = (const float*)d_in[7];
  const float* bv      = (const float*)d_in[8];
  const float* wo      = (const float*)d_in[9];
  const float* bo      = (const float*)d_in[10];
  const float* phi_w   = (const float*)d_in[11];
  const float* phi_b   = (const float*)d_in[12];
  const float* glob_w  = (const float*)d_in[13];
  const float* gc1_w   = (const float*)d_in[14];
  const float* gc2_w   = (const float*)d_in[15];
  const float* gw_w    = (const float*)d_in[16];
  const float* s2l_w   = (const float*)d_in[17];
  const float* final_w = (const float*)d_in[19];
  float* out = (float*)d_out;

  float* W = (float*)d_ws;
  // zero region [0, 4960 floats): bar | rg | n1 | xsum | fmaxb | cmaxb
  int*   bar   = (int*)W;          // 32 ints
  float* rg    = W + 32;           // 256
  float* n1    = W + 288;          // 304
  float* xsum  = W + 592;          // 4096
  float* fmaxb = W + 4688;         // 256
  float* cmaxb = W + 4944;         // 16
  float* qkv   = W + 4960;         // 18000
  float* n2    = W + 22960;        // 304
  float* h1    = W + 23264;        // 5120
  float* h2    = W + 28384;        // 5120
  float* u     = W + 33504;        // 256
  float* s_raw = W + 33760;        // 16384
  float* mcol  = W + 50144;        // 16384
  float* csum  = W + 66528;        // 16384
  float* dgd   = W + 82912;        // 256
  bf16_t* M16 = (bf16_t*)((char*)d_ws + 335872);   // 128 KB
  bf16_t* fBT = (bf16_t*)((char*)d_ws + 466944);   // 1 MB   (16 x 1024 x 32)
  bf16_t* fBn = (bf16_t*)((char*)d_ws + 1515520);  // 512 KB (16 x 16 x 1024, phi-flat)
  bf16_t* xTg = (bf16_t*)((char*)d_ws + 2039808);  // 8 MB   (16 x 256 x 1024)
  // total ws usage ~10.0 MB

  hipMemsetAsync(d_ws, 0, 4960 * sizeof(float), stream);
  k_phis <<<dim3(9, 16), 256, 0, stream>>>(x, phi_w, phi_b, s2l_w, fBT, fBn, fmaxb, s_raw, xsum, csum, cmaxb);
  k_trans<<<dim3(16, 16), 256, 0, stream>>>(x, xTg);
  k_M    <<<256, 256, 0, stream>>>(final_w, gw_w, M16);
  k_graph<<<20, 320, 0, stream>>>(emb, adj, wq, bq, wk, bk, wv, bv, wo, bo,
                                  gc1_w, gc2_w, final_w, bar, qkv, n1, n2, h1, h2, rg, u);
  k_dgm  <<<16, 256, 0, stream>>>(xsum, glob_w, s_raw, dgd, mcol);
  k_main <<<256, 512, 0, stream>>>(x, fBT, fBn, xTg, M16, fmaxb, mcol, u, dgd, csum, cmaxb, out);
}